// Round 1
// baseline (97.287 us; speedup 1.0000x reference)
//
#include <hip/hip_runtime.h>
#include <hip/hip_bf16.h>

// KANLinear as fragment-direct bf16 MFMA GEMM, 2-kernel structure:
//   y = hatA @ W''^T + skip_b
//   Skip connection FOLDED into weights: since sum_k hat_k(t)*grid_k = clamp(x)
//   exactly (piecewise-linear identity reproduction), prep bakes
//     W''[o][d*16+k] = values[o,d,k] + grid_k * skip_w[o,d]
//   so K = 4096 (no skip split). 8 uniform K-splits x 64 mi = 512 blocks
//   (exactly 2/CU). Split-K reduction fused into the GEMM: per mi-group the
//   last-arriving block (agent-scope ACQ_REL counter => buffer_wbl2/inv sc1
//   cross-XCD visibility) sums the 8 partial slabs and writes out + bias.
//   No kan_reduce kernel, no third launch, no cold partial re-read.
// A (2048 x 4096) VIRTUAL: per dim d, 16 hat weights max(0,1-|t-k|),
//   t=(clamp(x)+1)*7.5. A tiles (32 x 64) built cooperatively in LDS,
//   double-buffered, 1 barrier/step. W'' PRE-PERMUTED into MFMA B-fragment
//   order (Wf): one coalesced 16B load per 16x32 B-frag per lane.

namespace {
constexpr int Bsz  = 2048;
constexpr int Din  = 256;
constexpr int Dout = 256;
constexpr int Kn   = 16;
constexpr int KKNOT = Din * Kn;        // 4096 = full K (skip folded in)
constexpr int KB    = KKNOT / 32;      // 128 k-blocks of 32
constexpr float INV_H = 7.5f;          // 1 / (2/15)
constexpr float Hgrid = 2.0f / 15.0f;

constexpr int NSPLIT = 8;              // uniform K-splits (16 kblocks each)
constexpr int STK    = 8;              // steps per split (2 kblocks each)
constexpr int SXS    = 36;             // sx row stride (floats) -> conflict-free
}

typedef __attribute__((ext_vector_type(8))) short shortx8;   // 8 bf16 = 4 VGPR
typedef __attribute__((ext_vector_type(4))) float floatx4;   // MFMA acc

__device__ __forceinline__ unsigned int f2bf(float f) {
  __hip_bfloat16 h = __float2bfloat16(f);
  return (unsigned int)*reinterpret_cast<unsigned short*>(&h);
}
__device__ __forceinline__ float clamp1(float v) {
  return fminf(1.f, fmaxf(-1.f, v));
}
// Pack two pre-rounded f32 bit patterns (already +0x8000) into bf16x2.
__device__ __forceinline__ unsigned int packbf(unsigned int e0, unsigned int e1) {
  return (e1 & 0xffff0000u) | (e0 >> 16);
}
__device__ __forceinline__ unsigned int rnd(float f) {
  return __float_as_uint(f) + 0x8000u;
}

// --- Prep: fold skip into values, permute into B-fragment order; zero cnt.
//     Grid: 512 blocks x 256.  chunk(kb,og,q,n) lane layout matches gemm.
__global__ __launch_bounds__(256) void kan_prep(
    const float* __restrict__ values, const float* __restrict__ skip_w,
    unsigned short* __restrict__ Wf, unsigned int* __restrict__ cnt) {
  if (blockIdx.x == 0 && threadIdx.x < 64) cnt[threadIdx.x] = 0u;
  const int tid = blockIdx.x * 256 + threadIdx.x;   // 131072 total
  const int q  = tid & 3;
  const int n  = (tid >> 2) & 15;
  const int og = (tid >> 6) & 15;
  const int kb = tid >> 10;                          // 0..127
  const int o  = og * 16 + n;
  const int k0 = kb * 32 + q * 8;                    // 8 consecutive k, same dim
  const int d  = k0 >> 4;
  const float h0 = (float)(k0 & 15);                 // 0 or 8
  const float sw = skip_w[o * Din + d];
  const float* src = values + (size_t)o * KKNOT + k0;
  const float4 v0 = *(const float4*)src;
  const float4 v1 = *(const float4*)(src + 4);
  float e[8] = {v0.x, v0.y, v0.z, v0.w, v1.x, v1.y, v1.z, v1.w};
  #pragma unroll
  for (int j = 0; j < 8; ++j)
    e[j] = fmaf(-1.f + (h0 + (float)j) * Hgrid, sw, e[j]);  // + grid_k * skip_w
  const size_t chunk = (size_t)kb * 1024 + og * 64 + q * 16 + n;
  *(uint4*)(Wf + chunk * 8) = make_uint4(
      f2bf(e[0]) | (f2bf(e[1]) << 16), f2bf(e[2]) | (f2bf(e[3]) << 16),
      f2bf(e[4]) | (f2bf(e[5]) << 16), f2bf(e[6]) | (f2bf(e[7]) << 16));
}

// --- GEMM + fused split-K reduce: grid = 8 ks x 64 mi = 512 blocks, 256 thr.
//     ks = blockIdx.x>>6 so same-mi blocks are stride-64 (same XCD under
//     round-robin -> partial slabs L2/IF$-local); correctness via fences only.
__global__ __launch_bounds__(256) void kan_gemm(
    const float* __restrict__ x, const unsigned short* __restrict__ Wf,
    const float* __restrict__ skip_b, float* __restrict__ part,
    unsigned int* __restrict__ cnt, float* __restrict__ out) {
  __shared__ float sx[32 * SXS];                            // x slice, 4.6 KB
  __shared__ __align__(16) unsigned short aLds[2][32 * 64]; // A tiles, 2x4 KB
  __shared__ int s_last;

  const int tid  = threadIdx.x;
  const int wave = tid >> 6, lane = tid & 63;
  const int ks   = blockIdx.x >> 6;              // 0..7
  const int mi   = blockIdx.x & 63;              // 0..63
  const int m0   = mi * 32;
  const int og0  = wave * 4;                     // this wave's 64 out-cols
  const int lrow = lane & 15, lq = lane >> 4;

  // Cooperative A-build mapping: thread -> (row, 8-col segment of 64).
  const int brow = tid >> 3;                     // 0..31
  const int bseg = tid & 7;                      // cols bseg*8 .. +7
  const int kbi  = bseg >> 2;                    // which kblock of the pair
  const int dsel = (bseg >> 1) & 1;              // which of 2 dims in a kblock
  const float h0 = (float)((bseg & 1) * 8);      // hat base within dim

  const uint4* B = (const uint4*)Wf;             // chunk = kb*1024 + og*64 + lane

  floatx4 acc[2][4] = {};
  uint4 bb[2][8];

  const int kb0 = ks * 16;
  const int d0  = ks * 32;
  // Stage x slice: one float4 per thread (row = tid>>3, seg = tid&7).
  {
    const float4 v = *(const float4*)(x + (size_t)(m0 + brow) * Din + d0 + bseg * 4);
    *(float4*)&sx[brow * SXS + bseg * 4] = v;
  }
  __syncthreads();

  // Prolog: prefetch step-0 B-frags (2 kblocks) and build A-tile buf 0.
  #pragma unroll
  for (int kk = 0; kk < 2; ++kk)
    #pragma unroll
    for (int j = 0; j < 4; ++j)
      bb[0][kk * 4 + j] = B[(size_t)(kb0 + kk) * 1024 + (og0 + j) * 64 + lane];
  {
    const float xv = sx[brow * SXS + 2 * kbi + dsel];   // dims 0..3 for s=0
    const float t  = (clamp1(xv) + 1.f) * INV_H;
    unsigned int e[8];
    #pragma unroll
    for (int h = 0; h < 8; ++h)
      e[h] = rnd(fmaxf(0.f, 1.f - fabsf(t - (h0 + (float)h))));
    *(uint4*)&aLds[0][brow * 64 + bseg * 8] =
        make_uint4(packbf(e[0], e[1]), packbf(e[2], e[3]),
                   packbf(e[4], e[5]), packbf(e[6], e[7]));
  }

  for (int s = 0; s < STK; ++s) {
    const int cur = s & 1, nxt = cur ^ 1;
    // Prefetch next step's B-frags (2 kblocks).
    if (s + 1 < STK) {
      #pragma unroll
      for (int kk = 0; kk < 2; ++kk)
        #pragma unroll
        for (int j = 0; j < 4; ++j)
          bb[nxt][kk * 4 + j] =
              B[(size_t)(kb0 + 2 * (s + 1) + kk) * 1024 + (og0 + j) * 64 + lane];
    }
    __syncthreads();   // aLds[cur] visible; prior reads of nxt done

    // Build NEXT A-tile (from LDS sx, no global dependency).
    if (s + 1 < STK) {
      const float xv = sx[brow * SXS + 4 * (s + 1) + 2 * kbi + dsel];
      const float t  = (clamp1(xv) + 1.f) * INV_H;
      unsigned int e[8];
      #pragma unroll
      for (int h = 0; h < 8; ++h)
        e[h] = rnd(fmaxf(0.f, 1.f - fabsf(t - (h0 + (float)h))));
      *(uint4*)&aLds[nxt][brow * 64 + bseg * 8] =
          make_uint4(packbf(e[0], e[1]), packbf(e[2], e[3]),
                     packbf(e[4], e[5]), packbf(e[6], e[7]));
    }

    // A-frags (ds_read_b128) + 16 MFMA.
    shortx8 af[2][2];
    #pragma unroll
    for (int i = 0; i < 2; ++i)
      #pragma unroll
      for (int kk = 0; kk < 2; ++kk)
        af[i][kk] = *(const shortx8*)&aLds[cur][(16 * i + lrow) * 64 + kk * 32 + lq * 8];
    #pragma unroll
    for (int kk = 0; kk < 2; ++kk)
      #pragma unroll
      for (int j = 0; j < 4; ++j) {
        union { uint4 u; shortx8 s; } bc;
        bc.u = bb[cur][kk * 4 + j];
        #pragma unroll
        for (int i = 0; i < 2; ++i)
          acc[i][j] = __builtin_amdgcn_mfma_f32_16x16x32_bf16(af[i][kk], bc.s, acc[i][j], 0, 0, 0);
      }
  }

  // Write partial slab: per (mi,ks) 8192 floats contiguous; 1KB-coalesced.
  float4* P4 = (float4*)part;
  const size_t sbase = ((size_t)mi * NSPLIT + ks) * 2048 + wave * 512;
  #pragma unroll
  for (int i = 0; i < 2; ++i)
    #pragma unroll
    for (int j = 0; j < 4; ++j)
      P4[sbase + (i * 4 + j) * 64 + lane] =
          make_float4(acc[i][j][0], acc[i][j][1], acc[i][j][2], acc[i][j][3]);
  __syncthreads();   // all block stores complete (vmcnt(0) before barrier)

  // Last-arriver reduction. ACQ_REL agent-scope RMW: release makes this
  // block's partial stores visible device-wide (L2 writeback); the acquire
  // on the final increment invalidates stale L1/L2 so plain loads below see
  // all 8 slabs (incl. cross-XCD, incl. prior graph-replay iterations).
  if (tid == 0) {
    unsigned int old = __hip_atomic_fetch_add(&cnt[mi], 1u, __ATOMIC_ACQ_REL,
                                              __HIP_MEMORY_SCOPE_AGENT);
    s_last = (old == NSPLIT - 1);
  }
  __syncthreads();
  if (s_last) {
    const float4* Pm = (const float4*)part + (size_t)mi * NSPLIT * 2048;
    #pragma unroll
    for (int p = 0; p < 8; ++p) {
      const int g = p * 256 + tid;                 // f4 index within mi tile
      float4 a = Pm[g];
      #pragma unroll
      for (int sp = 1; sp < NSPLIT; ++sp) {
        const float4 b = Pm[sp * 2048 + g];
        a.x += b.x; a.y += b.y; a.z += b.z; a.w += b.w;
      }
      // Decode tile-blocked layout back to (b, o).
      const int w  = g >> 9, qq = g & 511;
      const int ij = qq >> 6, ln = qq & 63;
      const int i  = ij >> 2, j = ij & 3;
      const int b0 = mi * 32 + 16 * i + ((ln >> 4) << 2);
      const int o  = w * 64 + 16 * j + (ln & 15);
      const float sb = skip_b[o];
      out[(size_t)(b0 + 0) * Dout + o] = a.x + sb;
      out[(size_t)(b0 + 1) * Dout + o] = a.y + sb;
      out[(size_t)(b0 + 2) * Dout + o] = a.z + sb;
      out[(size_t)(b0 + 3) * Dout + o] = a.w + sb;
    }
  }
}

// ---------------- Fallback (round-1 structure, needs 4.4 MB ws) ----------------
__device__ __forceinline__ void knot_interp(float xraw, float& xv, float& w, int& l) {
  xv = fminf(1.0f, fmaxf(-1.0f, xraw));
  float t = (xv + 1.0f) * INV_H;
  l = (int)ceilf(t) - 1;
  l = l < 0 ? 0 : (l > Kn - 2 ? Kn - 2 : l);
  float g0 = -1.0f + Hgrid * (float)l;
  w = (xv - g0) * INV_H;
}

__global__ __launch_bounds__(256) void prep_transpose(
    const float* __restrict__ values, const float* __restrict__ skip_w,
    float* __restrict__ vt, float* __restrict__ swt) {
  int idx = blockIdx.x * blockDim.x + threadIdx.x;
  if (idx < Din * Kn * Dout) {
    int k = idx & (Kn - 1);
    int d = (idx >> 4) & (Din - 1);
    int o = idx >> 12;
    vt[(d * Kn + k) * Dout + o] = values[idx];
  }
  if (idx < Dout * Din) {
    int d = idx & (Din - 1);
    int o = idx >> 8;
    swt[d * Dout + o] = skip_w[idx];
  }
}

__global__ __launch_bounds__(256) void kan_main(
    const float* __restrict__ x, const float* __restrict__ vt,
    const float* __restrict__ swt, const float* __restrict__ skip_b,
    float* __restrict__ out) {
  __shared__ float s_w[4][Din];
  __shared__ float s_x[4][Din];
  __shared__ int   s_l[4][Din];
  const int tid = threadIdx.x;
  const int b0  = blockIdx.x * 4;
  for (int i = tid; i < 4 * Din; i += 256) {
    int bb = i >> 8;
    int d  = i & (Din - 1);
    float xv, w; int l;
    knot_interp(x[(b0 + bb) * Din + d], xv, w, l);
    s_w[bb][d] = w; s_x[bb][d] = xv; s_l[bb][d] = l;
  }
  __syncthreads();
  const int g = tid >> 6, lane = tid & 63;
  const int o = lane << 2, b = b0 + g;
  float4 acc = make_float4(0.f, 0.f, 0.f, 0.f);
  for (int d = 0; d < Din; ++d) {
    const float w = s_w[g][d], xv = s_x[g][d];
    const int l = s_l[g][d];
    const float* base = vt + (d * Kn + l) * Dout + o;
    const float4 vl = *(const float4*)(base);
    const float4 vr = *(const float4*)(base + Dout);
    const float4 sw = *(const float4*)(swt + d * Dout + o);
    acc.x = fmaf(xv, sw.x, fmaf(w, vr.x - vl.x, acc.x + vl.x));
    acc.y = fmaf(xv, sw.y, fmaf(w, vr.y - vl.y, acc.y + vl.y));
    acc.z = fmaf(xv, sw.z, fmaf(w, vr.z - vl.z, acc.z + vl.z));
    acc.w = fmaf(xv, sw.w, fmaf(w, vr.w - vl.w, acc.w + vl.w));
  }
  const float4 bias = *(const float4*)(skip_b + o);
  acc.x += bias.x; acc.y += bias.y; acc.z += bias.z; acc.w += bias.w;
  *(float4*)(out + (size_t)b * Dout + o) = acc;
}

extern "C" void kernel_launch(void* const* d_in, const int* in_sizes, int n_in,
                              void* d_out, int out_size, void* d_ws, size_t ws_size,
                              hipStream_t stream) {
  (void)in_sizes; (void)n_in; (void)out_size;
  const float* x      = (const float*)d_in[0];
  const float* values = (const float*)d_in[1];
  const float* skip_w = (const float*)d_in[2];
  const float* skip_b = (const float*)d_in[3];
  float* out = (float*)d_out;

  const size_t wf_bytes   = (size_t)Dout * KKNOT * sizeof(unsigned short); // 2.10 MB
  const size_t cnt_bytes  = 256;                                           // 64 u32, padded
  const size_t part_bytes = (size_t)64 * NSPLIT * 8192 * sizeof(float);    // 16.78 MB
  const size_t need_gemm  = wf_bytes + cnt_bytes + part_bytes;
  const size_t need_fb    = (size_t)(Din * Kn * Dout + Din * Dout) * sizeof(float);

  if (ws_size >= need_gemm) {
    unsigned short* Wf = (unsigned short*)d_ws;
    unsigned int* cnt  = (unsigned int*)((char*)d_ws + wf_bytes);
    float* part        = (float*)((char*)d_ws + wf_bytes + cnt_bytes);
    kan_prep<<<(KB * 1024) / 256, 256, 0, stream>>>(values, skip_w, Wf, cnt);
    kan_gemm<<<64 * NSPLIT, 256, 0, stream>>>(x, Wf, skip_b, part, cnt, out);
  } else if (ws_size >= need_fb) {
    float* vt  = (float*)d_ws;
    float* swt = vt + Din * Kn * Dout;
    prep_transpose<<<(Din * Kn * Dout + 255) / 256, 256, 0, stream>>>(values, skip_w, vt, swt);
    kan_main<<<Bsz / 4, 256, 0, stream>>>(x, vt, swt, skip_b, out);
  }
}

// Round 2
// 78.102 us; speedup vs baseline: 1.2456x; 1.2456x over previous
//
#include <hip/hip_runtime.h>
#include <hip/hip_bf16.h>

// KANLinear as fragment-direct bf16 MFMA GEMM, 3-kernel structure:
//   y = hatA @ W''^T + skip_b
//   Skip connection FOLDED into weights (verified R1, absmax unchanged):
//   sum_k hat_k(t)*grid_k = clamp(x) exactly (piecewise-linear identity
//   reproduction), so prep bakes
//     W''[o][d*16+k] = values[o,d,k] + grid_k * skip_w[o,d]
//   => K = 4096, 8 uniform K-splits x 64 mi = 512 blocks (exactly 2/CU).
// Split-K reduced by a SEPARATE kernel: the kernel-launch boundary provides
//   cross-XCD visibility for free. R1's fused last-arriver reduction
//   regressed ~10us: 512 agent-scope ACQ_REL RMWs emit buffer_wbl2/inv sc1
//   (whole-L2 writeback+invalidate on non-coherent per-XCD L2s), nuking the
//   L2-resident Wf panels under still-running sibling blocks, and the 64
//   reducer blocks ran at 1/8 machine occupancy on cold L2. Reverted.
// A (2048 x 4096) VIRTUAL: per dim d, 16 hat weights max(0,1-|t-k|),
//   t=(clamp(x)+1)*7.5. A tiles (32 x 64) built cooperatively in LDS,
//   double-buffered, 1 barrier/step. W'' PRE-PERMUTED into MFMA B-fragment
//   order (Wf): one coalesced 16B load per 16x32 B-frag per lane.
// Partials: mi-major contiguous slabs part[(mi*8+ks)*8192 ..] so each
//   reducer thread's 8 loads sit in one 256KB slab (stride 32KB).

namespace {
constexpr int Bsz  = 2048;
constexpr int Din  = 256;
constexpr int Dout = 256;
constexpr int Kn   = 16;
constexpr int KKNOT = Din * Kn;        // 4096 = full K (skip folded in)
constexpr int KB    = KKNOT / 32;      // 128 k-blocks of 32
constexpr float INV_H = 7.5f;          // 1 / (2/15)
constexpr float Hgrid = 2.0f / 15.0f;

constexpr int NSPLIT = 8;              // uniform K-splits (16 kblocks each)
constexpr int STK    = 8;              // steps per split (2 kblocks each)
constexpr int SXS    = 36;             // sx row stride (floats) -> conflict-free
}

typedef __attribute__((ext_vector_type(8))) short shortx8;   // 8 bf16 = 4 VGPR
typedef __attribute__((ext_vector_type(4))) float floatx4;   // MFMA acc

__device__ __forceinline__ unsigned int f2bf(float f) {
  __hip_bfloat16 h = __float2bfloat16(f);
  return (unsigned int)*reinterpret_cast<unsigned short*>(&h);
}
__device__ __forceinline__ float clamp1(float v) {
  return fminf(1.f, fmaxf(-1.f, v));
}
// Pack two pre-rounded f32 bit patterns (already +0x8000) into bf16x2.
__device__ __forceinline__ unsigned int packbf(unsigned int e0, unsigned int e1) {
  return (e1 & 0xffff0000u) | (e0 >> 16);
}
__device__ __forceinline__ unsigned int rnd(float f) {
  return __float_as_uint(f) + 0x8000u;
}

// --- Prep: fold skip into values, permute into B-fragment order.
//     Grid: 512 blocks x 256.  chunk(kb,og,q,n) lane layout matches gemm.
__global__ __launch_bounds__(256) void kan_prep(
    const float* __restrict__ values, const float* __restrict__ skip_w,
    unsigned short* __restrict__ Wf) {
  const int tid = blockIdx.x * 256 + threadIdx.x;   // 131072 total
  const int q  = tid & 3;
  const int n  = (tid >> 2) & 15;
  const int og = (tid >> 6) & 15;
  const int kb = tid >> 10;                          // 0..127
  const int o  = og * 16 + n;
  const int k0 = kb * 32 + q * 8;                    // 8 consecutive k, same dim
  const int d  = k0 >> 4;
  const float h0 = (float)(k0 & 15);                 // 0 or 8
  const float sw = skip_w[o * Din + d];
  const float* src = values + (size_t)o * KKNOT + k0;
  const float4 v0 = *(const float4*)src;
  const float4 v1 = *(const float4*)(src + 4);
  float e[8] = {v0.x, v0.y, v0.z, v0.w, v1.x, v1.y, v1.z, v1.w};
  #pragma unroll
  for (int j = 0; j < 8; ++j)
    e[j] = fmaf(-1.f + (h0 + (float)j) * Hgrid, sw, e[j]);  // + grid_k * skip_w
  const size_t chunk = (size_t)kb * 1024 + og * 64 + q * 16 + n;
  *(uint4*)(Wf + chunk * 8) = make_uint4(
      f2bf(e[0]) | (f2bf(e[1]) << 16), f2bf(e[2]) | (f2bf(e[3]) << 16),
      f2bf(e[4]) | (f2bf(e[5]) << 16), f2bf(e[6]) | (f2bf(e[7]) << 16));
}

// --- GEMM: grid = 8 ks x 64 mi = 512 blocks, 256 thr (4 waves).
//     ks = blockIdx.x>>6 so same-ks blocks (sharing a Wf slice) are
//     consecutive -> spread across XCDs, each XCD L2 caches all slices (2.1MB).
__global__ __launch_bounds__(256) void kan_gemm(
    const float* __restrict__ x, const unsigned short* __restrict__ Wf,
    float* __restrict__ part) {
  __shared__ float sx[32 * SXS];                            // x slice, 4.6 KB
  __shared__ __align__(16) unsigned short aLds[2][32 * 64]; // A tiles, 2x4 KB

  const int tid  = threadIdx.x;
  const int wave = tid >> 6, lane = tid & 63;
  const int ks   = blockIdx.x >> 6;              // 0..7
  const int mi   = blockIdx.x & 63;              // 0..63
  const int m0   = mi * 32;
  const int og0  = wave * 4;                     // this wave's 64 out-cols
  const int lrow = lane & 15, lq = lane >> 4;

  // Cooperative A-build mapping: thread -> (row, 8-col segment of 64).
  const int brow = tid >> 3;                     // 0..31
  const int bseg = tid & 7;                      // cols bseg*8 .. +7
  const int kbi  = bseg >> 2;                    // which kblock of the pair
  const int dsel = (bseg >> 1) & 1;              // which of 2 dims in a kblock
  const float h0 = (float)((bseg & 1) * 8);      // hat base within dim

  const uint4* B = (const uint4*)Wf;             // chunk = kb*1024 + og*64 + lane

  floatx4 acc[2][4] = {};
  uint4 bb[2][8];

  const int kb0 = ks * 16;
  const int d0  = ks * 32;
  // Stage x slice: one float4 per thread (row = tid>>3, seg = tid&7).
  {
    const float4 v = *(const float4*)(x + (size_t)(m0 + brow) * Din + d0 + bseg * 4);
    *(float4*)&sx[brow * SXS + bseg * 4] = v;
  }
  __syncthreads();

  // Prolog: prefetch step-0 B-frags (2 kblocks) and build A-tile buf 0.
  #pragma unroll
  for (int kk = 0; kk < 2; ++kk)
    #pragma unroll
    for (int j = 0; j < 4; ++j)
      bb[0][kk * 4 + j] = B[(size_t)(kb0 + kk) * 1024 + (og0 + j) * 64 + lane];
  {
    const float xv = sx[brow * SXS + 2 * kbi + dsel];   // dims 0..3 for s=0
    const float t  = (clamp1(xv) + 1.f) * INV_H;
    unsigned int e[8];
    #pragma unroll
    for (int h = 0; h < 8; ++h)
      e[h] = rnd(fmaxf(0.f, 1.f - fabsf(t - (h0 + (float)h))));
    *(uint4*)&aLds[0][brow * 64 + bseg * 8] =
        make_uint4(packbf(e[0], e[1]), packbf(e[2], e[3]),
                   packbf(e[4], e[5]), packbf(e[6], e[7]));
  }

  for (int s = 0; s < STK; ++s) {
    const int cur = s & 1, nxt = cur ^ 1;
    // Prefetch next step's B-frags (2 kblocks).
    if (s + 1 < STK) {
      #pragma unroll
      for (int kk = 0; kk < 2; ++kk)
        #pragma unroll
        for (int j = 0; j < 4; ++j)
          bb[nxt][kk * 4 + j] =
              B[(size_t)(kb0 + 2 * (s + 1) + kk) * 1024 + (og0 + j) * 64 + lane];
    }
    __syncthreads();   // aLds[cur] visible; prior reads of nxt done

    // Build NEXT A-tile (from LDS sx, no global dependency).
    if (s + 1 < STK) {
      const float xv = sx[brow * SXS + 4 * (s + 1) + 2 * kbi + dsel];
      const float t  = (clamp1(xv) + 1.f) * INV_H;
      unsigned int e[8];
      #pragma unroll
      for (int h = 0; h < 8; ++h)
        e[h] = rnd(fmaxf(0.f, 1.f - fabsf(t - (h0 + (float)h))));
      *(uint4*)&aLds[nxt][brow * 64 + bseg * 8] =
          make_uint4(packbf(e[0], e[1]), packbf(e[2], e[3]),
                     packbf(e[4], e[5]), packbf(e[6], e[7]));
    }

    // A-frags (ds_read_b128) + 16 MFMA.
    shortx8 af[2][2];
    #pragma unroll
    for (int i = 0; i < 2; ++i)
      #pragma unroll
      for (int kk = 0; kk < 2; ++kk)
        af[i][kk] = *(const shortx8*)&aLds[cur][(16 * i + lrow) * 64 + kk * 32 + lq * 8];
    #pragma unroll
    for (int kk = 0; kk < 2; ++kk)
      #pragma unroll
      for (int j = 0; j < 4; ++j) {
        union { uint4 u; shortx8 s; } bc;
        bc.u = bb[cur][kk * 4 + j];
        #pragma unroll
        for (int i = 0; i < 2; ++i)
          acc[i][j] = __builtin_amdgcn_mfma_f32_16x16x32_bf16(af[i][kk], bc.s, acc[i][j], 0, 0, 0);
      }
  }

  // Write partial slab: per (mi,ks) 8192 floats contiguous; 1KB-coalesced.
  float4* P4 = (float4*)part;
  const size_t sbase = ((size_t)mi * NSPLIT + ks) * 2048 + wave * 512;
  #pragma unroll
  for (int i = 0; i < 2; ++i)
    #pragma unroll
    for (int j = 0; j < 4; ++j)
      P4[sbase + (i * 4 + j) * 64 + lane] =
          make_float4(acc[i][j][0], acc[i][j][1], acc[i][j][2], acc[i][j][3]);
}

// --- Reduce 8 mi-major slab partials + bias -> out. 512 blocks x 256.
//     Per thread: 8 float4 loads within one 256KB mi-slab (stride 32KB),
//     fully coalesced per wave; decode tile-blocked layout -> (b, o).
__global__ __launch_bounds__(256) void kan_reduce(
    const float* __restrict__ part, const float* __restrict__ skip_b,
    float* __restrict__ out) {
  const int mi = blockIdx.x >> 3;                       // 0..63
  const int g  = ((blockIdx.x & 7) << 8) + threadIdx.x; // f4 idx in [0,2048)
  const float4* Pm = (const float4*)part + (size_t)mi * NSPLIT * 2048;
  float4 a = Pm[g];
  #pragma unroll
  for (int sp = 1; sp < NSPLIT; ++sp) {
    const float4 b = Pm[sp * 2048 + g];
    a.x += b.x; a.y += b.y; a.z += b.z; a.w += b.w;
  }
  const int w  = g >> 9, qq = g & 511;
  const int ij = qq >> 6, ln = qq & 63;
  const int i  = ij >> 2, j = ij & 3;
  const int b0 = mi * 32 + 16 * i + ((ln >> 4) << 2);
  const int o  = w * 64 + 16 * j + (ln & 15);
  const float sb = skip_b[o];
  out[(size_t)(b0 + 0) * Dout + o] = a.x + sb;
  out[(size_t)(b0 + 1) * Dout + o] = a.y + sb;
  out[(size_t)(b0 + 2) * Dout + o] = a.z + sb;
  out[(size_t)(b0 + 3) * Dout + o] = a.w + sb;
}

// ---------------- Fallback (round-1 structure, needs 4.4 MB ws) ----------------
__device__ __forceinline__ void knot_interp(float xraw, float& xv, float& w, int& l) {
  xv = fminf(1.0f, fmaxf(-1.0f, xraw));
  float t = (xv + 1.0f) * INV_H;
  l = (int)ceilf(t) - 1;
  l = l < 0 ? 0 : (l > Kn - 2 ? Kn - 2 : l);
  float g0 = -1.0f + Hgrid * (float)l;
  w = (xv - g0) * INV_H;
}

__global__ __launch_bounds__(256) void prep_transpose(
    const float* __restrict__ values, const float* __restrict__ skip_w,
    float* __restrict__ vt, float* __restrict__ swt) {
  int idx = blockIdx.x * blockDim.x + threadIdx.x;
  if (idx < Din * Kn * Dout) {
    int k = idx & (Kn - 1);
    int d = (idx >> 4) & (Din - 1);
    int o = idx >> 12;
    vt[(d * Kn + k) * Dout + o] = values[idx];
  }
  if (idx < Dout * Din) {
    int d = idx & (Din - 1);
    int o = idx >> 8;
    swt[d * Dout + o] = skip_w[idx];
  }
}

__global__ __launch_bounds__(256) void kan_main(
    const float* __restrict__ x, const float* __restrict__ vt,
    const float* __restrict__ swt, const float* __restrict__ skip_b,
    float* __restrict__ out) {
  __shared__ float s_w[4][Din];
  __shared__ float s_x[4][Din];
  __shared__ int   s_l[4][Din];
  const int tid = threadIdx.x;
  const int b0  = blockIdx.x * 4;
  for (int i = tid; i < 4 * Din; i += 256) {
    int bb = i >> 8;
    int d  = i & (Din - 1);
    float xv, w; int l;
    knot_interp(x[(b0 + bb) * Din + d], xv, w, l);
    s_w[bb][d] = w; s_x[bb][d] = xv; s_l[bb][d] = l;
  }
  __syncthreads();
  const int g = tid >> 6, lane = tid & 63;
  const int o = lane << 2, b = b0 + g;
  float4 acc = make_float4(0.f, 0.f, 0.f, 0.f);
  for (int d = 0; d < Din; ++d) {
    const float w = s_w[g][d], xv = s_x[g][d];
    const int l = s_l[g][d];
    const float* base = vt + (d * Kn + l) * Dout + o;
    const float4 vl = *(const float4*)(base);
    const float4 vr = *(const float4*)(base + Dout);
    const float4 sw = *(const float4*)(swt + d * Dout + o);
    acc.x = fmaf(xv, sw.x, fmaf(w, vr.x - vl.x, acc.x + vl.x));
    acc.y = fmaf(xv, sw.y, fmaf(w, vr.y - vl.y, acc.y + vl.y));
    acc.z = fmaf(xv, sw.z, fmaf(w, vr.z - vl.z, acc.z + vl.z));
    acc.w = fmaf(xv, sw.w, fmaf(w, vr.w - vl.w, acc.w + vl.w));
  }
  const float4 bias = *(const float4*)(skip_b + o);
  acc.x += bias.x; acc.y += bias.y; acc.z += bias.z; acc.w += bias.w;
  *(float4*)(out + (size_t)b * Dout + o) = acc;
}

extern "C" void kernel_launch(void* const* d_in, const int* in_sizes, int n_in,
                              void* d_out, int out_size, void* d_ws, size_t ws_size,
                              hipStream_t stream) {
  (void)in_sizes; (void)n_in; (void)out_size;
  const float* x      = (const float*)d_in[0];
  const float* values = (const float*)d_in[1];
  const float* skip_w = (const float*)d_in[2];
  const float* skip_b = (const float*)d_in[3];
  float* out = (float*)d_out;

  const size_t wf_bytes   = (size_t)Dout * KKNOT * sizeof(unsigned short); // 2.10 MB
  const size_t part_bytes = (size_t)64 * NSPLIT * 8192 * sizeof(float);    // 16.78 MB
  const size_t need_gemm  = wf_bytes + part_bytes;
  const size_t need_fb    = (size_t)(Din * Kn * Dout + Din * Dout) * sizeof(float);

  if (ws_size >= need_gemm) {
    unsigned short* Wf = (unsigned short*)d_ws;
    float* part        = (float*)((char*)d_ws + wf_bytes);
    kan_prep<<<(KB * 1024) / 256, 256, 0, stream>>>(values, skip_w, Wf);
    kan_gemm<<<64 * NSPLIT, 256, 0, stream>>>(x, Wf, part);
    kan_reduce<<<512, 256, 0, stream>>>(part, skip_b, out);
  } else if (ws_size >= need_fb) {
    float* vt  = (float*)d_ws;
    float* swt = vt + Din * Kn * Dout;
    prep_transpose<<<(Din * Kn * Dout + 255) / 256, 256, 0, stream>>>(values, skip_w, vt, swt);
    kan_main<<<Bsz / 4, 256, 0, stream>>>(x, vt, swt, skip_b, out);
  }
}